// Round 1
// baseline (228.092 us; speedup 1.0000x reference)
//
#include <hip/hip_runtime.h>
#include <cmath>

#define IN_SZ  448
#define OUT_SZ 224
#define RPB    8      // output rows per block

__device__ __forceinline__ float sig10(float z) {
    // jax.nn.sigmoid(10*z); expf overflow/underflow saturates to 0/1 correctly
    return 1.0f / (1.0f + expf(-10.0f * z));
}

__global__ __launch_bounds__(256) void racnn_kernel(
    const float* __restrict__ img,
    const float* __restrict__ locs,
    float* __restrict__ out)
{
    const int b   = blockIdx.y;
    const int rg  = blockIdx.x;   // row group: rows [rg*RPB, rg*RPB+RPB)
    const int tid = threadIdx.x;

    __shared__ int   s_r0[RPB], s_r1[RPB];
    __shared__ float s_a0[RPB], s_a1[RPB];

    // ---- per-batch scalars (redundant per thread, cheap) ----
    float tx = locs[b * 3 + 0];
    float ty = locs[b * 3 + 1];
    float tl = locs[b * 3 + 2];
    tl = fmaxf(tl, (float)IN_SZ / 3.0f);
    tx = fminf(fmaxf(tx, tl), (float)IN_SZ - tl);
    ty = fminf(fmaxf(ty, tl), (float)IN_SZ - tl);
    const float w_off = fmaxf(floorf(tx - tl), 0.0f);
    const float h_off = fmaxf(floorf(ty - tl), 0.0f);
    const float w_end = fminf(floorf(tx + tl), (float)IN_SZ);
    const float h_end = fminf(floorf(ty + tl), (float)IN_SZ);

    // ---- row coefficients for this block's RPB rows (into LDS) ----
    if (tid < RPB) {
        int jr = rg * RPB + tid;
        float src_r = w_off + (float)jr * (w_end - w_off - 1.0f) / (float)(OUT_SZ - 1);
        float r0 = fminf(fmaxf(floorf(src_r), 0.0f), (float)(IN_SZ - 1));
        float wr = src_r - r0;
        int r0i = (int)r0;
        int r1i = min(r0i + 1, IN_SZ - 1);
        float m0 = sig10(r0 - w_off) - sig10(r0 - w_end);
        float m1 = sig10((float)r1i - w_off) - sig10((float)r1i - w_end);
        s_r0[tid] = r0i;
        s_r1[tid] = r1i;
        s_a0[tid] = (1.0f - wr) * m0;
        s_a1[tid] = wr * m1;
    }

    // ---- column coefficients: thread = column jc = tid (registers) ----
    int   c0i = 0, c1i = 0;
    float b0 = 0.0f, b1 = 0.0f;
    if (tid < OUT_SZ) {
        float src_c = h_off + (float)tid * (h_end - h_off - 1.0f) / (float)(OUT_SZ - 1);
        float c0 = fminf(fmaxf(floorf(src_c), 0.0f), (float)(IN_SZ - 1));
        float wc = src_c - c0;
        c0i = (int)c0;
        c1i = min(c0i + 1, IN_SZ - 1);
        float m0 = sig10(c0 - h_off) - sig10(c0 - h_end);
        float m1 = sig10((float)c1i - h_off) - sig10((float)c1i - h_end);
        b0 = (1.0f - wc) * m0;
        b1 = wc * m1;
    }

    __syncthreads();
    if (tid >= OUT_SZ) return;   // 32 idle lanes past column 223; no later barrier

    const size_t img_b = (size_t)b * 3 * IN_SZ * IN_SZ;
    const size_t out_b = (size_t)b * 3 * OUT_SZ * OUT_SZ;

    #pragma unroll
    for (int ch = 0; ch < 3; ++ch) {
        const float* cbase = img + img_b + (size_t)ch * IN_SZ * IN_SZ;
        float* obase = out + out_b + (size_t)ch * OUT_SZ * OUT_SZ
                     + (size_t)(rg * RPB) * OUT_SZ + tid;
        #pragma unroll
        for (int k = 0; k < RPB; ++k) {
            const float* row0 = cbase + s_r0[k] * IN_SZ;
            const float* row1 = cbase + s_r1[k] * IN_SZ;
            float x00 = row0[c0i];
            float x01 = row0[c1i];
            float x10 = row1[c0i];
            float x11 = row1[c1i];
            float v = s_a0[k] * (b0 * x00 + b1 * x01)
                    + s_a1[k] * (b0 * x10 + b1 * x11);
            obase[(size_t)k * OUT_SZ] = v;
        }
    }
}

extern "C" void kernel_launch(void* const* d_in, const int* in_sizes, int n_in,
                              void* d_out, int out_size, void* d_ws, size_t ws_size,
                              hipStream_t stream) {
    const float* img  = (const float*)d_in[0];
    const float* locs = (const float*)d_in[1];
    float* out = (float*)d_out;
    const int B = in_sizes[1] / 3;                 // 64
    dim3 grid(OUT_SZ / RPB, B);                    // 28 x 64 = 1792 blocks
    racnn_kernel<<<grid, 256, 0, stream>>>(img, locs, out);
}

// Round 2
// 223.500 us; speedup vs baseline: 1.0205x; 1.0205x over previous
//
#include <hip/hip_runtime.h>
#include <cmath>

#define IN_SZ   448
#define OUT_SZ  224
#define RPB     8                 // output rows per block
#define NROWS   18                // max distinct input rows needed: ceil(7*2.005)+2 <= 17
#define ROWF4   (IN_SZ / 4)       // 112 float4 per full row

__device__ __forceinline__ float sig10(float z) {
    return 1.0f / (1.0f + expf(-10.0f * z));
}

__global__ __launch_bounds__(256) void racnn_kernel(
    const float* __restrict__ img,
    const float* __restrict__ locs,
    float* __restrict__ out)
{
    const int b   = blockIdx.y;
    const int rg  = blockIdx.x;          // rows [rg*RPB, rg*RPB+RPB)
    const int tid = threadIdx.x;

    __shared__ float s_img[NROWS * IN_SZ];          // 32256 B staged window
    __shared__ int   s_r0[RPB], s_r1[RPB];
    __shared__ float s_a0[RPB], s_a1[RPB];

    // ---- per-batch scalars (redundant per thread) ----
    float tx = locs[b * 3 + 0];
    float ty = locs[b * 3 + 1];
    float tl = locs[b * 3 + 2];
    tl = fmaxf(tl, (float)IN_SZ / 3.0f);
    tx = fminf(fmaxf(tx, tl), (float)IN_SZ - tl);
    ty = fminf(fmaxf(ty, tl), (float)IN_SZ - tl);
    const float w_off = fmaxf(floorf(tx - tl), 0.0f);
    const float h_off = fmaxf(floorf(ty - tl), 0.0f);
    const float w_end = fminf(floorf(tx + tl), (float)IN_SZ);
    const float h_end = fminf(floorf(ty + tl), (float)IN_SZ);

    const float rstep = (w_end - w_off - 1.0f) / (float)(OUT_SZ - 1);
    const float cstep = (h_end - h_off - 1.0f) / (float)(OUT_SZ - 1);

    // ---- row coefficients for this block's RPB rows (LDS) ----
    if (tid < RPB) {
        int jr = rg * RPB + tid;
        float src_r = w_off + (float)jr * rstep;
        float r0 = fminf(fmaxf(floorf(src_r), 0.0f), (float)(IN_SZ - 1));
        float wr = src_r - r0;
        int r0i = (int)r0;
        int r1i = min(r0i + 1, IN_SZ - 1);
        float m0 = sig10(r0 - w_off) - sig10(r0 - w_end);
        float m1 = sig10((float)r1i - w_off) - sig10((float)r1i - w_end);
        s_r0[tid] = r0i;
        s_r1[tid] = r1i;
        s_a0[tid] = (1.0f - wr) * m0;
        s_a1[tid] = wr * m1;
    }

    // ---- column coefficients: thread = column (registers) ----
    int   c0i, c1i;
    float cb0, cb1;
    {
        float src_c = h_off + (float)min(tid, OUT_SZ - 1) * cstep;
        float c0 = fminf(fmaxf(floorf(src_c), 0.0f), (float)(IN_SZ - 1));
        float wc = src_c - c0;
        c0i = (int)c0;
        c1i = min(c0i + 1, IN_SZ - 1);
        float m0 = sig10(c0 - h_off) - sig10(c0 - h_end);
        float m1 = sig10((float)c1i - h_off) - sig10((float)c1i - h_end);
        cb0 = (1.0f - wc) * m0;
        cb1 = wc * m1;
    }

    // ---- staging window bounds (every thread computes; all identical) ----
    int row_lo  = (int)fminf(fmaxf(floorf(w_off + (float)(rg * RPB) * rstep), 0.0f), (float)(IN_SZ - 1));
    int r0_last = (int)fminf(fmaxf(floorf(w_off + (float)(rg * RPB + RPB - 1) * rstep), 0.0f), (float)(IN_SZ - 1));
    int row_hi  = min(r0_last + 1, IN_SZ - 1);
    int nrows   = row_hi - row_lo + 1;               // <= NROWS

    int c_lo  = (int)fminf(fmaxf(floorf(h_off), 0.0f), (float)(IN_SZ - 1));
    int chl   = (int)fminf(fmaxf(floorf(h_off + (float)(OUT_SZ - 1) * cstep), 0.0f), (float)(IN_SZ - 1));
    int c_hi  = min(chl + 1, IN_SZ - 1);
    int c4base = c_lo >> 2;                          // 16B-aligned column start
    int nf4    = (c_hi >> 2) - c4base + 1;           // float4s per staged row

    const size_t img_b = (size_t)b * 3 * IN_SZ * IN_SZ;
    const size_t out_b = (size_t)b * 3 * OUT_SZ * OUT_SZ;

    const int lr = tid >> 7;      // 0/1: two rows staged per iteration
    const int lc = tid & 127;     // column-float4 within row

    for (int ch = 0; ch < 3; ++ch) {
        __syncthreads();          // first iter: covers coeff writes; later: s_img reuse
        const float4* src4 = (const float4*)(img + img_b + (size_t)ch * IN_SZ * IN_SZ);
        float4* dst4 = (float4*)s_img;
        #pragma unroll
        for (int rr = 0; rr < NROWS; rr += 2) {
            int r = rr + lr;
            if (r < nrows && lc < nf4) {
                dst4[r * ROWF4 + c4base + lc] = src4[(size_t)(row_lo + r) * ROWF4 + c4base + lc];
            }
        }
        __syncthreads();
        if (tid < OUT_SZ) {
            float* obase = out + out_b + (size_t)ch * OUT_SZ * OUT_SZ
                         + (size_t)(rg * RPB) * OUT_SZ + tid;
            #pragma unroll
            for (int k = 0; k < RPB; ++k) {
                const float* p0 = s_img + (s_r0[k] - row_lo) * IN_SZ;
                const float* p1 = s_img + (s_r1[k] - row_lo) * IN_SZ;
                float x00 = p0[c0i], x01 = p0[c1i];
                float x10 = p1[c0i], x11 = p1[c1i];
                obase[(size_t)k * OUT_SZ] =
                    s_a0[k] * (cb0 * x00 + cb1 * x01) + s_a1[k] * (cb0 * x10 + cb1 * x11);
            }
        }
    }
}

extern "C" void kernel_launch(void* const* d_in, const int* in_sizes, int n_in,
                              void* d_out, int out_size, void* d_ws, size_t ws_size,
                              hipStream_t stream) {
    const float* img  = (const float*)d_in[0];
    const float* locs = (const float*)d_in[1];
    float* out = (float*)d_out;
    const int B = in_sizes[1] / 3;                   // 64
    dim3 grid(OUT_SZ / RPB, B);                      // 28 x 64 = 1792 blocks
    racnn_kernel<<<grid, 256, 0, stream>>>(img, locs, out);
}